// Round 3
// baseline (237.056 us; speedup 1.0000x reference)
//
#include <hip/hip_runtime.h>
#include <stdint.h>

// PennSkipGramModel forward. R1/R2 lesson: compiler re-serializes register
// gathers (VGPR stuck at 36, ~1 load in flight/wave, latency-bound at 2.5 TB/s).
// R3: structural MLP via async global->LDS DMA (__builtin_amdgcn_global_load_lds):
// one wave per batch element, 7 DMA instrs stage all 14 rows (2 rows/instr:
// lanes 0-31 row A, lanes 32-63 row B, 16 B/lane, wave-uniform LDS base),
// fire-and-forget then a single vmcnt(0) before LDS consumption. Payload lives
// in LDS, not VGPRs -> scheduler cannot sink the loads.

#define HV     128                      // floats per row (HALF)
#define BATCH  65536
#define K      5
#define NBLK   1024
#define WPB    4                        // waves per block (256 thr)
#define ITERS  (BATCH / (NBLK * WPB))   // 16 batch elements per wave
#define WBUF   (14 * HV)                // 1792 floats = 7168 B per wave stage

struct Idx { int iu, ivl, ivr, nl[K], nr[K]; };

__device__ __forceinline__ Idx load_idx(const int* pu, const int* pvl, const int* pvr,
                                        const int* nvl, const int* nvr, int b) {
    Idx x;
    x.iu  = pu[b];  x.ivl = pvl[b];  x.ivr = pvr[b];
    #pragma unroll
    for (int k = 0; k < K; ++k) { x.nl[k] = nvl[b*K + k]; x.nr[k] = nvr[b*K + k]; }
    return x;
}

// One instruction stages two 512B rows: lane<32 -> rowA, else rowB; HW writes
// each lane's 16B to ldsBase + lane*16 (wave-uniform base + lane*size).
__device__ __forceinline__ void dma_pair(const float* rowA, const float* rowB,
                                         float* ldsBase, int lane) {
    const float* g = ((lane < 32) ? rowA : rowB) + (lane & 31) * 4;
    __builtin_amdgcn_global_load_lds(
        (const __attribute__((address_space(1))) void*)g,
        (__attribute__((address_space(3))) void*)ldsBase,
        16, 0, 0);
}

__device__ __forceinline__ float2 rd2(const float* buf, int off, int lane) {
    return *(const float2*)(buf + off + 2 * lane);
}
__device__ __forceinline__ float dot2(float2 a, float2 b) { return a.x*b.x + a.y*b.y; }
__device__ __forceinline__ float clip10(float x) { return fminf(fmaxf(x, -10.f), 10.f); }

__global__ __launch_bounds__(256) void skipgram_fwd(
    const float* __restrict__ u_l, const float* __restrict__ u_r,
    const float* __restrict__ v_l, const float* __restrict__ v_r,
    const int* __restrict__ pos_u, const int* __restrict__ pos_vl,
    const int* __restrict__ pos_vr, const int* __restrict__ neg_vl,
    const int* __restrict__ neg_vr, float* __restrict__ out)
{
    __shared__ float stage[WPB][WBUF];
    __shared__ float wsum[WPB];

    const int tid  = threadIdx.x;
    const int lane = tid & 63;
    const int wv   = tid >> 6;
    const int b0   = (blockIdx.x * WPB + wv) * ITERS;
    float* buf = &stage[wv][0];

    float acc = 0.0f;
    Idx cur = load_idx(pos_u, pos_vl, pos_vr, neg_vl, neg_vr, b0);

    for (int it = 0; it < ITERS; ++it) {
        // ---- issue all 7 DMAs for current b (async, no VGPR payload) ----
        dma_pair(u_l + (size_t)cur.iu   * HV, u_r + (size_t)cur.iu   * HV, buf + 0*256, lane);
        dma_pair(v_l + (size_t)cur.ivl  * HV, v_r + (size_t)cur.ivr  * HV, buf + 1*256, lane);
        dma_pair(v_l + (size_t)cur.nl[0]* HV, v_l + (size_t)cur.nl[1]* HV, buf + 2*256, lane);
        dma_pair(v_l + (size_t)cur.nl[2]* HV, v_l + (size_t)cur.nl[3]* HV, buf + 3*256, lane);
        dma_pair(v_l + (size_t)cur.nl[4]* HV, v_r + (size_t)cur.nr[0]* HV, buf + 4*256, lane);
        dma_pair(v_r + (size_t)cur.nr[1]* HV, v_r + (size_t)cur.nr[2]* HV, buf + 5*256, lane);
        dma_pair(v_r + (size_t)cur.nr[3]* HV, v_r + (size_t)cur.nr[4]* HV, buf + 6*256, lane);

        // ---- prefetch next iteration's indices (wave-uniform -> SMEM) ----
        const int bn = b0 + ((it + 1 < ITERS) ? (it + 1) : 0);
        Idx nxt = load_idx(pos_u, pos_vl, pos_vr, neg_vl, neg_vr, bn);

        __builtin_amdgcn_s_waitcnt(0x0F70);   // vmcnt(0): DMAs landed in LDS
        __builtin_amdgcn_sched_barrier(0);    // keep ds_reads below the wait

        // LDS row offsets (floats): ul=0 ur=128 vl=256 vr=384
        // nl[k]=512+128k, nr[k]=1152+128k
        float2 u2l = rd2(buf, 0,   lane);
        float2 u2r = rd2(buf, 128, lane);
        float s[12];
        s[0] = dot2(u2l, rd2(buf, 256, lane));
        s[1] = dot2(u2r, rd2(buf, 384, lane));
        #pragma unroll
        for (int k = 0; k < K; ++k) {
            s[2 + k] = dot2(u2l, rd2(buf,  512 + 128*k, lane));
            s[7 + k] = dot2(u2r, rd2(buf, 1152 + 128*k, lane));
        }
        // 12 independent 64-lane butterflies, interleaved for ILP
        #pragma unroll
        for (int m = 1; m < 64; m <<= 1) {
            #pragma unroll
            for (int j = 0; j < 12; ++j) s[j] += __shfl_xor(s[j], m, 64);
        }
        acc += __logf(1.0f + __expf(-clip10(s[0])));   // -logsig(pos_l)
        acc += __logf(1.0f + __expf(-clip10(s[1])));   // -logsig(pos_r)
        #pragma unroll
        for (int j = 2; j < 12; ++j)
            acc += __logf(1.0f + __expf(clip10(s[j]))); // -logsig(-neg)

        cur = nxt;
    }

    if (lane == 0) wsum[wv] = acc;
    __syncthreads();
    if (tid == 0) {
        float s = wsum[0] + wsum[1] + wsum[2] + wsum[3];
        atomicAdd(out, s * (1.0f / BATCH));
    }
}

extern "C" void kernel_launch(void* const* d_in, const int* in_sizes, int n_in,
                              void* d_out, int out_size, void* d_ws, size_t ws_size,
                              hipStream_t stream) {
    const float* u_l   = (const float*)d_in[0];
    const float* u_r   = (const float*)d_in[1];
    const float* v_l   = (const float*)d_in[2];
    const float* v_r   = (const float*)d_in[3];
    const int* pos_u   = (const int*)d_in[4];
    const int* pos_vl  = (const int*)d_in[5];
    const int* pos_vr  = (const int*)d_in[6];
    const int* neg_vl  = (const int*)d_in[7];
    const int* neg_vr  = (const int*)d_in[8];
    float* out = (float*)d_out;

    hipMemsetAsync(out, 0, sizeof(float), stream);

    skipgram_fwd<<<NBLK, 256, 0, stream>>>(
        u_l, u_r, v_l, v_r, pos_u, pos_vl, pos_vr, neg_vl, neg_vr, out);
}